// Round 4
// baseline (168.981 us; speedup 1.0000x reference)
//
#include <hip/hip_runtime.h>
#include <cfloat>
#include <stdint.h>

#define B_   16
#define N_   2048
#define KK   10          // window = K+1
#define H_   128
#define SUB  32          // chunk size
#define NCH  (N_ / SUB)  // 64 chunks

#define RANK_BLOCKS (B_ * 32)                  // 512: 64-elem segments, 256 thr
#define WEFF_OUT    (H_ * KK * 2 + H_)         // 2688 outputs
#define WEFF_BLOCKS ((WEFF_OUT * 4) / 256)     // 42 (4 lanes/output, exact)

__device__ inline uint32_t f32_ordered(float f) {
    uint32_t u = __float_as_uint(f);
    return (u & 0x80000000u) ? ~u : (u | 0x80000000u);
}

// ---- setup v3 (unchanged from R3, ~6us): rank-by-count sort. Keys
// (ordered_x<<32 | idx) unique -> rank = #{smaller} is an exact permutation,
// bitwise-identical output to the original bitonic sort.
__global__ __launch_bounds__(256) void setup_kernel(
    const float* __restrict__ x,
    const float* __restrict__ Wconv, const float* __restrict__ bconv,
    const float* __restrict__ b1,    const float* __restrict__ W2,
    const float* __restrict__ b2,
    float4* __restrict__ xsorted,    // [B][N] (px,py,sm,orig_idx_bits)
    float*  __restrict__ weff,       // [H*20]
    float*  __restrict__ btot)       // [H]
{
#pragma clang fp contract(off)
    __shared__ __align__(16) uint64_t sk[N_];   // 16 KB
    __shared__ int pcnt[4 * 64];
    const int tid = threadIdx.x;

    if (blockIdx.x >= RANK_BLOCKS) {
        // weff/btot: 4 lanes per output, 32 MACs each, shfl-reduce.
        const int g = (blockIdx.x - RANK_BLOCKS) * 256 + tid;
        const int o = g >> 2, q = g & 3;
        float acc = 0.f;
        if (o < H_ * KK * 2) {
            const int e = o / 20, r = o % 20, k = r >> 1, c = r & 1;
            const float* w2p = W2 + e * H_ + q * 32;
            const float* wcp = Wconv + (q * 32) * (2 * KK) + c * KK + k;
#pragma unroll 8
            for (int h = 0; h < 32; ++h)
                acc += w2p[h] * wcp[h * (2 * KK)];
        } else {
            const int e = o - H_ * KK * 2;
            const float* w2p = W2 + e * H_ + q * 32;
            const float* bcp = bconv + q * 32;
#pragma unroll 8
            for (int h = 0; h < 32; ++h) acc += w2p[h] * bcp[h];
        }
        acc += __shfl_xor(acc, 1, 64);
        acc += __shfl_xor(acc, 2, 64);
        if (q == 0) {
            if (o < H_ * KK * 2) weff[o] = acc;
            else {
                const int e = o - H_ * KK * 2;
                btot[e] = acc + b1[e] + b2[e];
            }
        }
        return;
    }

    const int b  = blockIdx.x >> 5;   // 32 seg-blocks per batch
    const int sg = blockIdx.x & 31;   // 64-element segment
    const float2* xb = (const float2*)(x + (size_t)b * N_ * 2);

    for (int i = tid; i < N_; i += 256)
        sk[i] = ((uint64_t)f32_ordered(xb[i].x) << 32) | (uint32_t)i;
    __syncthreads();

    const int el = tid & 63;
    const int pt = tid >> 6;
    const uint64_t kown = sk[sg * 64 + el];
    const ulonglong2* sk2 = (const ulonglong2*)sk + pt * 256;
    int cnt = 0;
#pragma unroll 2
    for (int j = 0; j < 256; j += 4) {
        ulonglong2 t0 = sk2[j + 0];
        ulonglong2 t1 = sk2[j + 1];
        ulonglong2 t2 = sk2[j + 2];
        ulonglong2 t3 = sk2[j + 3];
        cnt += (int)(t0.x < kown) + (int)(t0.y < kown)
             + (int)(t1.x < kown) + (int)(t1.y < kown)
             + (int)(t2.x < kown) + (int)(t2.y < kown)
             + (int)(t3.x < kown) + (int)(t3.y < kown);
    }
    pcnt[pt * 64 + el] = cnt;
    __syncthreads();

    if (tid < 64) {
        const int r = pcnt[tid] + pcnt[64 + tid] + pcnt[128 + tid] + pcnt[192 + tid];
        const int i = sg * 64 + tid;
        float2 p = xb[i];
        float sm = p.x * p.x + p.y * p.y;   // no FMA (np sum convention)
        xsorted[(size_t)b * N_ + r] =
            make_float4(p.x, p.y, sm, __uint_as_float((uint32_t)i));
    }
}

// ---- main kernel v4: 256 threads (4 waves) per 32 queries (= 1 chunk);
// 1024 blocks on 512 residency slots -> 4 dispatch rounds/CU-slot-pair
// -> hardware rebalances the dense/sparse tile imbalance (R3: occ 28% vs
// structural 50%, kernel = slowest CU). Wave w owns chunks == w (mod 4);
// lanes: q = l&31 (query), hh = l>>5 (even/odd positions of each chunk).
// 8 partial lists per query (4 waves x 2 halves) -> merge-8 unchanged.
// Merged top-10 is partition-invariant -> output bitwise identical to R3.
__global__ __launch_bounds__(256, 2) void knn_conv_kernel(
    const float4* __restrict__ xsorted,
    const float* __restrict__ W1,
    const float* __restrict__ weff,
    const float* __restrict__ btot,
    float* __restrict__ out)
{
#pragma clang fp contract(off)
    __shared__ float4   xs4[N_];          // 32 KB
    __shared__ uint64_t mkeys[32 * 81];   // 20.25 KB (8 lists x 10 + pad)
    __shared__ float    wcoord[32 * 21];  //  2.6 KB
    __shared__ float    hbound[32 * 9];   //  1.1 KB (stride 9: conflict-free)

    const int tid  = threadIdx.x;
    const int w    = tid >> 6;        // wave 0..3
    const int l    = tid & 63;
    const int q    = l & 31;          // query within tile
    const int hh   = l >> 5;          // 0: even chunk positions, 1: odd
    const int b    = blockIdx.x >> 6;
    const int tile = blockIdx.x & 63; // tile == chunk index

    const float4* xb = xsorted + (size_t)b * N_;
    for (int i = tid; i < N_; i += 256) xs4[i] = xb[i];
    __syncthreads();

    const int    n  = tile * 32 + q;
    const float4 qv = xs4[n];
    const float  qx = qv.x, qy = qv.y, sqn = qv.z;
    const float  qa  = xs4[tile * 32].x;       // tile x-range (uniform)
    const float  qbx = xs4[tile * 32 + 31].x;

    // sorted-10 of u64 keys: (d2_bits<<32)|(orig_idx<<11)|sorted_pos.
    const uint64_t KINIT = (((uint64_t)0x7F7FFFFFu) << 32) | 0x3FFFFFu;
    uint64_t hk[KK];
#pragma unroll
    for (int j = 0; j < KK; ++j) hk[j] = KINIT;
    float h9d  = FLT_MAX;   // d2 of own 10th-best
    float shb  = FLT_MAX;   // shared bound (min over 8 lists, after phase 1)
    float gate = FLT_MAX;   // fminf(h9d, shb)

    auto insert = [&](float dc, float cw, int m) {
        uint32_t oi = __float_as_uint(cw);
        uint64_t key = ((uint64_t)__float_as_uint(dc) << 32)
                     | (oi << 11) | (uint32_t)m;
        if (key < hk[KK - 1]) {
#pragma unroll
            for (int j = KK - 1; j >= 1; --j) {
                bool cj  = key < hk[j];
                bool cjm = key < hk[j - 1];
                hk[j] = cj ? (cjm ? hk[j - 1] : key) : hk[j];
            }
            hk[0] = (key < hk[0]) ? key : hk[0];
        }
        h9d  = __uint_as_float((uint32_t)(hk[KK - 1] >> 32));
        gate = fminf(h9d, shb);
    };

    // half hh scans positions mc+hh, mc+hh+2, ... (16 of 32, ILP-4 batched)
    auto scan_chunk = [&](int mc) {
        const int base = mc + hh;
#pragma unroll
        for (int jj = 0; jj < 4; ++jj) {
            const int m0 = base + jj * 8;
            float4 c0 = xs4[m0 + 0];
            float4 c1 = xs4[m0 + 2];
            float4 c2 = xs4[m0 + 4];
            float4 c3 = xs4[m0 + 6];
            float dc0, dc1, dc2, dc3;
            { float s = sqn + c0.z; float pr = qx * c0.x;
              float dt = __builtin_fmaf(qy, c0.y, pr);
              float d2 = __builtin_fmaf(-2.0f, dt, s); dc0 = d2 > 0.0f ? d2 : 0.0f; }
            { float s = sqn + c1.z; float pr = qx * c1.x;
              float dt = __builtin_fmaf(qy, c1.y, pr);
              float d2 = __builtin_fmaf(-2.0f, dt, s); dc1 = d2 > 0.0f ? d2 : 0.0f; }
            { float s = sqn + c2.z; float pr = qx * c2.x;
              float dt = __builtin_fmaf(qy, c2.y, pr);
              float d2 = __builtin_fmaf(-2.0f, dt, s); dc2 = d2 > 0.0f ? d2 : 0.0f; }
            { float s = sqn + c3.z; float pr = qx * c3.x;
              float dt = __builtin_fmaf(qy, c3.y, pr);
              float d2 = __builtin_fmaf(-2.0f, dt, s); dc3 = d2 > 0.0f ? d2 : 0.0f; }
            if (dc0 <= gate) insert(dc0, c0.w, m0 + 0);
            if (dc1 <= gate) insert(dc1, c1.w, m0 + 2);
            if (dc2 <= gate) insert(dc2, c2.w, m0 + 4);
            if (dc3 <= gate) insert(dc3, c3.w, m0 + 6);
        }
    };

    // phase 1: nearest owned chunk (mod 4); waves tile {ct-1, ct, ct+1, ct+2}
    const int ct  = tile;
    const int a   = (w - ct) & 3;
    const int c1_ = ct + a;
    const int c2_ = c1_ - 4;
    int c_near = (a <= 2) ? c1_ : c2_;
    if (c1_ > NCH - 1) c_near = c2_;
    if (c2_ < 0)       c_near = c1_;
    scan_chunk(c_near * SUB);

    // cross-list bound exchange: min over 8 partial 10th-bests (each list
    // holds 10 of >=16 real candidates) is a valid upper bound on the true
    // 10th-best -> safe block-wide gate.
    hbound[q * 9 + (w * 2 + hh)] = h9d;
    __syncthreads();
    {
        const float* hb = &hbound[q * 9];
        float m0 = fminf(hb[0], hb[1]);
        float m1 = fminf(hb[2], hb[3]);
        float m2 = fminf(hb[4], hb[5]);
        float m3 = fminf(hb[6], hb[7]);
        shb  = fminf(fminf(m0, m1), fminf(m2, m3));
        gate = fminf(h9d, shb);
    }

    // phase 2: two-pointer outward expansion (step 4); wave-uniform control.
    int  cl = c_near - 4, cr = c_near + 4;
    bool la = (cl >= 0), ra = (cr <= NCH - 1);
    while (la || ra) {
        float wm = gate;
        wm = fmaxf(wm, __shfl_xor(wm, 1,  64));
        wm = fmaxf(wm, __shfl_xor(wm, 2,  64));
        wm = fmaxf(wm, __shfl_xor(wm, 4,  64));
        wm = fmaxf(wm, __shfl_xor(wm, 8,  64));
        wm = fmaxf(wm, __shfl_xor(wm, 16, 64));
        wm = fmaxf(wm, __shfl_xor(wm, 32, 64));
        float gl = la ? (qa - xs4[cl * SUB + SUB - 1].x) : FLT_MAX;  // >= 0
        float gr = ra ? (xs4[cr * SUB].x - qbx)          : FLT_MAX;  // >= 0
        bool pickL = la && (!ra || gl <= gr);
        if (pickL) {
            if (__builtin_fmaf(gl, gl, -4e-6f) > wm) la = false;  // margin >> f32 d2 err
            else { scan_chunk(cl * SUB); cl -= 4; la = (cl >= 0); }
        } else {
            if (__builtin_fmaf(gr, gr, -4e-6f) > wm) ra = false;
            else { scan_chunk(cr * SUB); cr += 4; ra = (cr <= NCH - 1); }
        }
    }

    // publish partial lists: list li = w*2+hh of query q
    {
        const int mb = q * 81 + (w * 2 + hh) * 10;
#pragma unroll
        for (int j = 0; j < KK; ++j) mkeys[mb + j] = hk[j];
    }

    // hoist epilogue weights (latency overlaps the barrier)
    const int e = tid & 127;
    float we[20];
    {
        const float4* wp = (const float4*)(weff + e * 20);
#pragma unroll
        for (int r = 0; r < 5; ++r) {
            float4 v = wp[r];
            we[4 * r + 0] = v.x; we[4 * r + 1] = v.y;
            we[4 * r + 2] = v.z; we[4 * r + 3] = v.w;
        }
    }
    const float w1x = W1[e * 2 + 0];
    const float w1y = W1[e * 2 + 1];
    const float bt  = btot[e];
    __syncthreads();

    // parallel merge: 8 lanes per query (qm = tid>>3 covers 32 queries,
    // r = tid&7 -> list). Keys unique -> exactly one winner per selection.
    {
        const int qm = tid >> 3;
        const int r  = tid & 7;
        const int mb = qm * 81 + r * 10;
        int p = 0;
#pragma unroll
        for (int sel = 0; sel < KK; ++sel) {
            uint64_t v = (p < KK) ? mkeys[mb + p] : 0xFFFFFFFFFFFFFFFFull;
            uint64_t t1 = __shfl_xor((unsigned long long)v, 1, 64);
            uint64_t m1 = v  < t1 ? v  : t1;
            uint64_t t2 = __shfl_xor((unsigned long long)m1, 2, 64);
            uint64_t m2 = m1 < t2 ? m1 : t2;
            uint64_t t4 = __shfl_xor((unsigned long long)m2, 4, 64);
            uint64_t vm = m2 < t4 ? m2 : t4;
            if (v == vm) {
                ++p;
                float4 c = xs4[(int)(vm & 0x7FF)];
                const int k = (KK - 1) - sel;          // flip: nearest -> k=9
                wcoord[qm * 21 + 2 * k + 0] = c.x;
                wcoord[qm * 21 + 2 * k + 1] = c.y;
            }
        }
    }
    __syncthreads();

    // epilogue: thread -> channel e; 2 base queries x 16 -> 32 queries.
    const int qb_ = tid >> 7;
    const size_t obase = (size_t)b * N_ * H_;
#pragma unroll
    for (int jj = 0; jj < 16; ++jj) {
        const int qq = qb_ + 2 * jj;
        float4 xq = xs4[tile * 32 + qq];
        uint32_t orig = __float_as_uint(xq.w);
        const float* wc = &wcoord[qq * 21];
        float acc = bt;
        acc += xq.x * w1x;
        acc += xq.y * w1y;
#pragma unroll
        for (int k = 0; k < KK; ++k) {
            acc += wc[2 * k + 0] * we[2 * k + 0];
            acc += wc[2 * k + 1] * we[2 * k + 1];
        }
        out[obase + (size_t)orig * H_ + e] = acc;
    }
}

extern "C" void kernel_launch(void* const* d_in, const int* in_sizes, int n_in,
                              void* d_out, int out_size, void* d_ws, size_t ws_size,
                              hipStream_t stream) {
    const float* x     = (const float*)d_in[0];
    const float* Wconv = (const float*)d_in[1];
    const float* bconv = (const float*)d_in[2];
    const float* W1    = (const float*)d_in[3];
    const float* b1    = (const float*)d_in[4];
    const float* W2    = (const float*)d_in[5];
    const float* b2    = (const float*)d_in[6];
    float* out  = (float*)d_out;
    float* weff = (float*)d_ws;                           // 2560 floats
    float* btot = weff + H_ * KK * 2;                     // 128 floats
    float4* xsorted = (float4*)((char*)d_ws + 16384);     // 16*2048*16B

    setup_kernel<<<dim3(RANK_BLOCKS + WEFF_BLOCKS), dim3(256), 0, stream>>>(
        x, Wconv, bconv, b1, W2, b2, xsorted, weff, btot);
    knn_conv_kernel<<<dim3(B_ * NCH), dim3(256), 0, stream>>>(
        xsorted, W1, weff, btot, out);
}